// Round 2
// baseline (311.249 us; speedup 1.0000x reference)
//
#include <hip/hip_runtime.h>
#include <hip/hip_bf16.h>

#define NUM_FIELDS 39
#define PER_FIELD_VOCAB 10000
#define EMBED_DIM 128
#define KPAD 64          // F padded to 64 for triple-term K-chunks of 32
#define NT 3             // W1 slabs (triple term); W0 pair handled via Gram trick
#define RANK 128
#define BATCH 2048
#define ET_STRIDE 72     // eT[d][f] row stride (bf16): 64+8 pad, 16B-aligned, banks spread
#define E_STRIDE 144     // e[f][d] row stride (bf16): 128+16 pad, 288B = 16B-aligned
#define FPAD 48          // F padded to 3 16-tiles for the Gram matrix

typedef __bf16  bf16x8  __attribute__((ext_vector_type(8)));
typedef float   f32x4   __attribute__((ext_vector_type(4)));

// ---------------------------------------------------------------------------
// Precompute (batch-independent, cheap):
//   blocks 0..95 : Wb[3][128][64] bf16 = W1 zero-padded in f   (triple term)
//   blocks 96..104: M01[48][48] f32 = W0[0]^T W0[1] zero-padded (pair term)
// ---------------------------------------------------------------------------
__global__ __launch_bounds__(256) void prep(const float* __restrict__ W0,
                                            const float* __restrict__ W1,
                                            __bf16* __restrict__ Wb,
                                            float* __restrict__ M01) {
    int blk = blockIdx.x;
    if (blk < 96) {
        int i = blk * 256 + threadIdx.x;          // 3*128*64 = 24576
        int f = i & (KPAD - 1);
        int r = (i >> 6) & (RANK - 1);
        int l = i >> 13;
        float v = (f < NUM_FIELDS) ? W1[(l * RANK + r) * NUM_FIELDS + f] : 0.f;
        Wb[i] = (__bf16)v;
    } else {
        int j = (blk - 96) * 256 + threadIdx.x;   // 48*48 = 2304
        if (j < FPAD * FPAD) {
            int f0 = j / FPAD, f1 = j % FPAD;
            float s = 0.f;
            if (f0 < NUM_FIELDS && f1 < NUM_FIELDS) {
#pragma unroll 8
                for (int r = 0; r < RANK; ++r)
                    s += W0[r * NUM_FIELDS + f0] * W0[(RANK + r) * NUM_FIELDS + f1];
            }
            M01[j] = s;
        }
    }
}

// ---------------------------------------------------------------------------
// Main: one workgroup (256 thr = 4 waves) per batch element.
//   pair   = sum_{f,f'} G[f,f'] * M01[f,f'],  G = E E^T  (36 MFMAs)
//   triple = sum_{r,d} dp2*dp3*dp4, dp_l = W1_l E        (384 MFMAs)
// ---------------------------------------------------------------------------
__global__ __launch_bounds__(256) void tfm_main(const int* __restrict__ x,
                                                const float* __restrict__ embed_table,
                                                const float* __restrict__ linear_table,
                                                const float* __restrict__ bias,
                                                const __bf16* __restrict__ Wb,
                                                const float* __restrict__ M01,
                                                float* __restrict__ out,
                                                int out_size) {
    __shared__ int   sidx[NUM_FIELDS];
    __shared__ __align__(16) __bf16 eT[EMBED_DIM * ET_STRIDE]; // eT[d][f], 18432 B
    __shared__ __align__(16) __bf16 e [FPAD * E_STRIDE];       // e[f][d],  13824 B
    __shared__ float wpart[4];

    const int tid = threadIdx.x;
    const int b   = blockIdx.x;

    if (tid < NUM_FIELDS)
        sidx[tid] = x[b * NUM_FIELDS + tid] + tid * PER_FIELD_VOCAB;
    __syncthreads();

    // Gather emb rows -> LDS in BOTH layouts (bf16). Coalesced 512B per row read.
    for (int k = tid; k < NUM_FIELDS * EMBED_DIM; k += 256) {
        int f = k >> 7, d = k & (EMBED_DIM - 1);
        float v = embed_table[(size_t)sidx[f] * EMBED_DIM + d];
        __bf16 bv = (__bf16)v;
        eT[d * ET_STRIDE + f] = bv;   // triple-term B-operand layout
        e [f * E_STRIDE  + d] = bv;   // Gram-term A/B-operand layout
    }
    // Zero K-pad: eT rows f in [39,64), e rows f in [39,48).
    for (int k = tid; k < (KPAD - NUM_FIELDS) * EMBED_DIM; k += 256) {
        int f = NUM_FIELDS + (k >> 7), d = k & (EMBED_DIM - 1);
        eT[d * ET_STRIDE + f] = (__bf16)0.f;
    }
    for (int k = tid; k < (FPAD - NUM_FIELDS) * EMBED_DIM; k += 256) {
        int f = NUM_FIELDS + (k >> 7), d = k & (EMBED_DIM - 1);
        e[f * E_STRIDE + d] = (__bf16)0.f;
    }

    float partial = 0.f;
    if (tid < NUM_FIELDS) partial = linear_table[sidx[tid]];

    __syncthreads();

    const int wave = tid >> 6, lane = tid & 63;
    const int m = lane & 15, quad = lane >> 4;

    // --- Triple term: wave owns r-tiles {2w, 2w+1}; dt-outer so bfrag is shared.
    bf16x8 afrag[2][NT][2];  // [rti][l][kc]
#pragma unroll
    for (int rti = 0; rti < 2; ++rti) {
        const int r0 = (wave * 2 + rti) * 16;
#pragma unroll
        for (int l = 0; l < NT; ++l)
#pragma unroll
            for (int kc = 0; kc < 2; ++kc)
                afrag[rti][l][kc] = *reinterpret_cast<const bf16x8*>(
                    &Wb[((size_t)(l * RANK) + r0 + m) * KPAD + kc * 32 + quad * 8]);
    }

    float triplep = 0.f;
    for (int dt = 0; dt < 8; ++dt) {
        bf16x8 bfrag[2];
#pragma unroll
        for (int kc = 0; kc < 2; ++kc)
            bfrag[kc] = *reinterpret_cast<const bf16x8*>(
                &eT[(dt * 16 + m) * ET_STRIDE + kc * 32 + quad * 8]);
#pragma unroll
        for (int rti = 0; rti < 2; ++rti) {
            f32x4 acc[NT];
#pragma unroll
            for (int l = 0; l < NT; ++l) {
                acc[l] = (f32x4){0.f, 0.f, 0.f, 0.f};
#pragma unroll
                for (int kc = 0; kc < 2; ++kc)
                    acc[l] = __builtin_amdgcn_mfma_f32_16x16x32_bf16(
                        afrag[rti][l][kc], bfrag[kc], acc[l], 0, 0, 0);
            }
#pragma unroll
            for (int i = 0; i < 4; ++i)
                triplep += acc[0][i] * acc[1][i] * acc[2][i];
        }
    }

    // --- Pair term via Gram: 9 16x16 G-tiles round-robined over waves.
    float pairp = 0.f;
    for (int t = wave; t < 9; t += 4) {
        const int ti = t / 3, tj = t % 3;
        f32x4 g = (f32x4){0.f, 0.f, 0.f, 0.f};
#pragma unroll
        for (int kc = 0; kc < 4; ++kc) {
            bf16x8 ga = *reinterpret_cast<const bf16x8*>(
                &e[(ti * 16 + m) * E_STRIDE + kc * 32 + quad * 8]);
            bf16x8 gb = *reinterpret_cast<const bf16x8*>(
                &e[(tj * 16 + m) * E_STRIDE + kc * 32 + quad * 8]);
            g = __builtin_amdgcn_mfma_f32_16x16x32_bf16(ga, gb, g, 0, 0, 0);
        }
        // C/D layout: col = lane&15, row = quad*4 + i (verified by R0 pass).
#pragma unroll
        for (int i = 0; i < 4; ++i)
            pairp += g[i] * M01[(ti * 16 + quad * 4 + i) * FPAD + tj * 16 + m];
    }

    partial += triplep + pairp;

    // Block reduction.
#pragma unroll
    for (int off = 32; off > 0; off >>= 1)
        partial += __shfl_down(partial, off, 64);
    if (lane == 0) wpart[wave] = partial;
    __syncthreads();
    if (tid == 0)
        out[b] = wpart[0] + wpart[1] + wpart[2] + wpart[3] + bias[0];

    // Second tuple output ("0") and trailing pad.
    if (b == 0)
        for (int j = BATCH + tid; j < out_size; j += 256)
            out[j] = 0.f;
}

extern "C" void kernel_launch(void* const* d_in, const int* in_sizes, int n_in,
                              void* d_out, int out_size, void* d_ws, size_t ws_size,
                              hipStream_t stream) {
    const int*   x            = (const int*)d_in[0];
    const float* embed_table  = (const float*)d_in[1];
    const float* linear_table = (const float*)d_in[2];
    const float* bias         = (const float*)d_in[3];
    const float* W0           = (const float*)d_in[4];
    const float* W1           = (const float*)d_in[5];
    __bf16* Wb  = (__bf16*)d_ws;                          // 3*128*64*2 = 49152 B
    float*  M01 = (float*)((char*)d_ws + 49152);          // 48*48*4   =  9216 B

    prep<<<96 + 9, 256, 0, stream>>>(W0, W1, Wb, M01);
    tfm_main<<<BATCH, 256, 0, stream>>>(x, embed_table, linear_table, bias, Wb, M01,
                                        (float*)d_out, out_size);
}